// Round 1
// baseline (1284.677 us; speedup 1.0000x reference)
//
#include <hip/hip_runtime.h>
#include <math.h>

// LiteMLA fp32 baseline.
// Chunked over batch: 2 chunks x 8 batches; ws = qkv(100.7MB)+agg(100.7MB)+att(67MB)=268.4MB
// K1 k_qkv : GEMM 768x256 @ 256x(8*4096), BM=128 BN=64 BK=32, 8x4/thread
// K2 k_dwpw: fused depthwise 5x5 (pad2) + grouped 1x1 (48 groups of 16->16) via LDS tile
// K3 k_attn: per (head,b) linear attention: vk[17][16] reduce, then out = vk*q / denom
// K4 k_proj: GEMM 256x512 @ 512x(8*4096) + BN affine, BM=256 BN=64 BK=32, 16x4/thread

#define NBC 8  // batches per chunk

// ---------------- K1: qkv 1x1 conv ----------------
__global__ __launch_bounds__(256) void k_qkv(const float* __restrict__ x,
                                             const float* __restrict__ wq,
                                             float* __restrict__ qkv, int b0) {
    __shared__ float Wt[32][132];   // [k][m], padded
    __shared__ float Xs[32][64];    // [k][col]
    const int tid = threadIdx.x;
    const int tx = tid & 15, ty = tid >> 4;
    const int m0 = blockIdx.y * 128;
    const int cg = blockIdx.x * 64;      // column index within chunk
    const int bb = cg >> 12;
    const int p0 = cg & 4095;
    const float* xb = x + ((size_t)(b0 + bb) * 256) * 4096 + p0;

    float acc[8][4];
#pragma unroll
    for (int i = 0; i < 8; i++)
#pragma unroll
        for (int j = 0; j < 4; j++) acc[i][j] = 0.f;

    for (int kk = 0; kk < 256; kk += 32) {
#pragma unroll
        for (int l = 0; l < 16; l++) {
            int i = tid + l * 256;
            int k = i & 31, m = i >> 5;
            Wt[k][m] = wq[(size_t)(m0 + m) * 256 + kk + k];
        }
#pragma unroll
        for (int l = 0; l < 8; l++) {
            int i = tid + l * 256;
            int col = i & 63, kx = i >> 6;
            Xs[kx][col] = xb[(size_t)(kk + kx) * 4096 + col];
        }
        __syncthreads();
#pragma unroll
        for (int k = 0; k < 32; k++) {
            float4 a0 = *(const float4*)&Wt[k][ty * 8];
            float4 a1 = *(const float4*)&Wt[k][ty * 8 + 4];
            float4 bv = *(const float4*)&Xs[k][tx * 4];
            float av[8] = {a0.x, a0.y, a0.z, a0.w, a1.x, a1.y, a1.z, a1.w};
            float bl[4] = {bv.x, bv.y, bv.z, bv.w};
#pragma unroll
            for (int i = 0; i < 8; i++)
#pragma unroll
                for (int j = 0; j < 4; j++) acc[i][j] += av[i] * bl[j];
        }
        __syncthreads();
    }
    float* outp = qkv + ((size_t)bb * 768) * 4096 + p0;
#pragma unroll
    for (int i = 0; i < 8; i++) {
        int oc = m0 + ty * 8 + i;
        float4 v = make_float4(acc[i][0], acc[i][1], acc[i][2], acc[i][3]);
        *(float4*)&outp[(size_t)oc * 4096 + tx * 4] = v;
    }
}

// ---------------- K2: fused depthwise 5x5 + grouped pointwise ----------------
__global__ __launch_bounds__(256) void k_dwpw(const float* __restrict__ qkv,
                                              const float* __restrict__ wdw,
                                              const float* __restrict__ wpw,
                                              float* __restrict__ agg) {
    // grid: (yt 16, g 48, bb NBC); 4 output rows per block
    __shared__ float dwt[16 * 4 * 68];  // [ic][ry][x], row stride 68
    const int tid = threadIdx.x;
    const int yt = blockIdx.x, g = blockIdx.y, bb = blockIdx.z;

    // ---- depthwise phase: 16 ch x 16 x-quads ----
    {
        const int cl = tid >> 4, xq = tid & 15;
        const int c = g * 16 + cl;
        const float* in = qkv + ((size_t)bb * 768 + c) * 4096;
        float w[5][5];
#pragma unroll
        for (int dy = 0; dy < 5; dy++)
#pragma unroll
            for (int dx = 0; dx < 5; dx++) w[dy][dx] = wdw[c * 25 + dy * 5 + dx];
        const int x0 = xq * 4;
#pragma unroll
        for (int ry = 0; ry < 4; ry++) {
            int y = yt * 4 + ry;
            float o0 = 0.f, o1 = 0.f, o2 = 0.f, o3 = 0.f;
#pragma unroll
            for (int dy = 0; dy < 5; dy++) {
                int yy = y + dy - 2;
                if (yy < 0 || yy > 63) continue;
                const float* row = in + yy * 64;
                float4 v0 = (x0 >= 4) ? *(const float4*)&row[x0 - 4] : make_float4(0, 0, 0, 0);
                float4 v1 = *(const float4*)&row[x0];
                float4 v2 = (x0 + 4 < 64) ? *(const float4*)&row[x0 + 4] : make_float4(0, 0, 0, 0);
                float win[8] = {v0.z, v0.w, v1.x, v1.y, v1.z, v1.w, v2.x, v2.y};
#pragma unroll
                for (int dx = 0; dx < 5; dx++) {
                    float wv = w[dy][dx];
                    o0 += win[0 + dx] * wv;
                    o1 += win[1 + dx] * wv;
                    o2 += win[2 + dx] * wv;
                    o3 += win[3 + dx] * wv;
                }
            }
            float4 ov = make_float4(o0, o1, o2, o3);
            *(float4*)&dwt[(cl * 4 + ry) * 68 + x0] = ov;
        }
    }
    __syncthreads();

    // ---- grouped pointwise phase: 8 oc-pairs x 32 x-offsets ----
    {
        const int op = tid >> 5, xo = tid & 31;
        float wv[2][16];
#pragma unroll
        for (int oo = 0; oo < 2; oo++)
#pragma unroll
            for (int ic = 0; ic < 16; ic++)
                wv[oo][ic] = wpw[(size_t)(g * 16 + op * 2 + oo) * 16 + ic];
        float acc[2][4][2];
#pragma unroll
        for (int oo = 0; oo < 2; oo++)
#pragma unroll
            for (int j = 0; j < 4; j++) { acc[oo][j][0] = 0.f; acc[oo][j][1] = 0.f; }
#pragma unroll
        for (int ic = 0; ic < 16; ic++) {
#pragma unroll
            for (int j = 0; j < 4; j++) {
                float2 f = *(const float2*)&dwt[(ic * 4 + j) * 68 + xo * 2];
#pragma unroll
                for (int oo = 0; oo < 2; oo++) {
                    acc[oo][j][0] += wv[oo][ic] * f.x;
                    acc[oo][j][1] += wv[oo][ic] * f.y;
                }
            }
        }
#pragma unroll
        for (int oo = 0; oo < 2; oo++) {
            float* outp = agg + ((size_t)bb * 768 + g * 16 + op * 2 + oo) * 4096 + yt * 256;
#pragma unroll
            for (int j = 0; j < 4; j++) {
                float2 f = make_float2(acc[oo][j][0], acc[oo][j][1]);
                *(float2*)&outp[j * 64 + xo * 2] = f;
            }
        }
    }
}

// ---------------- K3: linear attention per (head, batch) ----------------
__global__ __launch_bounds__(256) void k_attn(const float* __restrict__ qkv,
                                              const float* __restrict__ agg,
                                              float* __restrict__ att) {
    // grid: (h 32, bb NBC)
    const int h = blockIdx.x, bb = blockIdx.y;
    const int tid = threadIdx.x;
    const float* src = (h < 16) ? qkv + ((size_t)bb * 768 + h * 48) * 4096
                                : agg + ((size_t)bb * 768 + (h - 16) * 48) * 4096;
    __shared__ float part[16 * 16 * 17];  // [jg][e][d]
    __shared__ float vks[17][17];

    // pass 1: vk[d][e] = sum_n vpad[d][n] * relu(k[e][n])
    {
        const int e = tid & 15, jg = tid >> 4;
        const float* kr = src + (size_t)(16 + e) * 4096 + jg * 256;
        const float* vr = src + (size_t)32 * 4096 + jg * 256;
        float a[17];
#pragma unroll
        for (int d = 0; d < 17; d++) a[d] = 0.f;
        for (int i = 0; i < 64; i++) {
            float4 kv = *(const float4*)&kr[i * 4];
            kv.x = fmaxf(kv.x, 0.f);
            kv.y = fmaxf(kv.y, 0.f);
            kv.z = fmaxf(kv.z, 0.f);
            kv.w = fmaxf(kv.w, 0.f);
#pragma unroll
            for (int d = 0; d < 16; d++) {
                float4 vv = *(const float4*)&vr[(size_t)d * 4096 + i * 4];
                a[d] += vv.x * kv.x + vv.y * kv.y + vv.z * kv.z + vv.w * kv.w;
            }
            a[16] += kv.x + kv.y + kv.z + kv.w;
        }
#pragma unroll
        for (int d = 0; d < 17; d++) part[(jg * 16 + e) * 17 + d] = a[d];
    }
    __syncthreads();
    for (int idx = tid; idx < 272; idx += 256) {
        int e = idx & 15, d = idx >> 4;
        float s = 0.f;
#pragma unroll
        for (int jg = 0; jg < 16; jg++) s += part[(jg * 16 + e) * 17 + d];
        vks[d][e] = s;
    }
    __syncthreads();

    // pass 2: out[d][n] = (sum_e vk[d][e]*relu(q[e][n])) / max(denom, eps)
    {
        float* outp = att + ((size_t)bb * 512 + h * 16) * 4096;
        for (int i = 0; i < 4; i++) {
            int n = tid * 4 + i * 1024;
            float4 q4[16];
#pragma unroll
            for (int e = 0; e < 16; e++) {
                float4 q = *(const float4*)&src[(size_t)e * 4096 + n];
                q.x = fmaxf(q.x, 0.f);
                q.y = fmaxf(q.y, 0.f);
                q.z = fmaxf(q.z, 0.f);
                q.w = fmaxf(q.w, 0.f);
                q4[e] = q;
            }
            float dx = 0.f, dy = 0.f, dz = 0.f, dw = 0.f;
#pragma unroll
            for (int e = 0; e < 16; e++) {
                float w = vks[16][e];
                dx += w * q4[e].x;
                dy += w * q4[e].y;
                dz += w * q4[e].z;
                dw += w * q4[e].w;
            }
            float rx = 1.f / fmaxf(dx, 1e-15f);
            float ry = 1.f / fmaxf(dy, 1e-15f);
            float rz = 1.f / fmaxf(dz, 1e-15f);
            float rw = 1.f / fmaxf(dw, 1e-15f);
#pragma unroll
            for (int d = 0; d < 16; d++) {
                float ox = 0.f, oy = 0.f, oz = 0.f, ow = 0.f;
#pragma unroll
                for (int e = 0; e < 16; e++) {
                    float w = vks[d][e];
                    ox += w * q4[e].x;
                    oy += w * q4[e].y;
                    oz += w * q4[e].z;
                    ow += w * q4[e].w;
                }
                float4 o = make_float4(ox * rx, oy * ry, oz * rz, ow * rw);
                *(float4*)&outp[(size_t)d * 4096 + n] = o;
            }
        }
    }
}

// ---------------- K4: output projection + BN ----------------
__global__ __launch_bounds__(256) void k_proj(const float* __restrict__ att,
                                              const float* __restrict__ wp,
                                              const float* __restrict__ gamma,
                                              const float* __restrict__ beta,
                                              const float* __restrict__ mean,
                                              const float* __restrict__ var,
                                              float* __restrict__ out, int b0) {
    __shared__ float Wt[32][260];  // [k][m], 256 rows + pad
    __shared__ float Xs[32][64];
    const int tid = threadIdx.x;
    const int tx = tid & 15, ty = tid >> 4;
    const int cg = blockIdx.x * 64;
    const int bb = cg >> 12, p0 = cg & 4095;
    const float* xb = att + ((size_t)bb * 512) * 4096 + p0;

    float acc[16][4];
#pragma unroll
    for (int i = 0; i < 16; i++)
#pragma unroll
        for (int j = 0; j < 4; j++) acc[i][j] = 0.f;

    for (int kk = 0; kk < 512; kk += 32) {
#pragma unroll
        for (int l = 0; l < 32; l++) {
            int i = tid + l * 256;
            int k = i & 31, m = i >> 5;
            Wt[k][m] = wp[(size_t)m * 512 + kk + k];
        }
#pragma unroll
        for (int l = 0; l < 8; l++) {
            int i = tid + l * 256;
            int col = i & 63, kx = i >> 6;
            Xs[kx][col] = xb[(size_t)(kk + kx) * 4096 + col];
        }
        __syncthreads();
#pragma unroll
        for (int k = 0; k < 32; k++) {
            float4 bv = *(const float4*)&Xs[k][tx * 4];
            float bl[4] = {bv.x, bv.y, bv.z, bv.w};
#pragma unroll
            for (int q = 0; q < 4; q++) {
                float4 a = *(const float4*)&Wt[k][ty * 16 + q * 4];
                float al[4] = {a.x, a.y, a.z, a.w};
#pragma unroll
                for (int j = 0; j < 4; j++)
#pragma unroll
                    for (int c = 0; c < 4; c++) acc[q * 4 + j][c] += al[j] * bl[c];
            }
        }
        __syncthreads();
    }
#pragma unroll
    for (int r = 0; r < 16; r++) {
        int oc = ty * 16 + r;
        float iv = gamma[oc] / sqrtf(var[oc] + 1e-5f);
        float bs = beta[oc] - mean[oc] * iv;
        float4 v = make_float4(acc[r][0] * iv + bs, acc[r][1] * iv + bs,
                               acc[r][2] * iv + bs, acc[r][3] * iv + bs);
        *(float4*)&out[((size_t)(b0 + bb) * 256 + oc) * 4096 + p0 + tx * 4] = v;
    }
}

extern "C" void kernel_launch(void* const* d_in, const int* in_sizes, int n_in,
                              void* d_out, int out_size, void* d_ws, size_t ws_size,
                              hipStream_t stream) {
    const float* x = (const float*)d_in[0];
    const float* wq = (const float*)d_in[1];
    const float* wdw = (const float*)d_in[2];
    const float* wpw = (const float*)d_in[3];
    const float* wp = (const float*)d_in[4];
    const float* gamma = (const float*)d_in[5];
    const float* beta = (const float*)d_in[6];
    const float* mean = (const float*)d_in[7];
    const float* var = (const float*)d_in[8];
    float* out = (float*)d_out;

    float* qkvb = (float*)d_ws;                 // NBC*768*4096 = 25165824 floats
    float* aggb = qkvb + (size_t)NBC * 768 * 4096;
    float* attb = aggb + (size_t)NBC * 768 * 4096;  // NBC*512*4096 floats

    for (int chunk = 0; chunk < 2; ++chunk) {
        int b0 = chunk * NBC;
        k_qkv<<<dim3(512, 6), 256, 0, stream>>>(x, wq, qkvb, b0);
        k_dwpw<<<dim3(16, 48, NBC), 256, 0, stream>>>(qkvb, wdw, wpw, aggb);
        k_attn<<<dim3(32, NBC), 256, 0, stream>>>(qkvb, aggb, attb);
        k_proj<<<dim3(512), 256, 0, stream>>>(attb, wp, gamma, beta, mean, var, out, b0);
    }
}

// Round 2
// 684.696 us; speedup vs baseline: 1.8763x; 1.8763x over previous
//
#include <hip/hip_runtime.h>
#include <math.h>

// LiteMLA bf16/MFMA pipeline. 2 chunks x 8 batches.
// K0 k_cvt_w : wq, wp fp32 -> bf16 (once)
// K1 k_tr_x  : x[c][n] fp32 -> xb_t[n][c] bf16 (per-batch transpose via LDS)
// K2 k_qkv_mm: D'[n][m] = xb_t * Wq^T via mfma_f32_16x16x32_bf16, no LDS,
//              direct per-lane 16B global frag loads, write qkv[c][n] bf16
// K3 k_dwpw  : fused depthwise 5x5 + grouped pointwise, bf16 io, fp32 math
// K4 k_attn  : linear attention fp32 math from bf16 q,k,v; writes att_t[n][512] bf16
// K5 k_proj_mm: D'[n][m] = att_t * Wp^T + BN affine, fp32 out

#define NBC 8

typedef unsigned short u16;
typedef __attribute__((ext_vector_type(8))) short short8v;
typedef __attribute__((ext_vector_type(8))) unsigned short us8;
typedef __attribute__((ext_vector_type(4))) float f32x4;

__device__ __forceinline__ u16 f2bf(float f) {
    union { float f; unsigned u; } v; v.f = f;
    unsigned r = v.u + 0x7fffu + ((v.u >> 16) & 1u);
    return (u16)(r >> 16);
}
__device__ __forceinline__ float bf2f(u16 u) {
    union { unsigned u; float f; } v; v.u = ((unsigned)u) << 16;
    return v.f;
}
__device__ __forceinline__ float4 ld4bf(const u16* p) {
    ushort4 u = *(const ushort4*)p;
    return make_float4(bf2f(u.x), bf2f(u.y), bf2f(u.z), bf2f(u.w));
}

// ---------------- K0: weight conversion ----------------
__global__ __launch_bounds__(256) void k_cvt_w(const float* __restrict__ wq,
                                               const float* __restrict__ wp,
                                               u16* __restrict__ wqb, u16* __restrict__ wpb) {
    int i = blockIdx.x * 256 + threadIdx.x;
    if (i < 768 * 256) wqb[i] = f2bf(wq[i]);
    if (i < 256 * 512) wpb[i] = f2bf(wp[i]);
}

// ---------------- K1: transpose x -> xb_t bf16 ----------------
__global__ __launch_bounds__(256) void k_tr_x(const float* __restrict__ x,
                                              u16* __restrict__ xbt, int b0) {
    __shared__ u16 t[64][72];
    const int nt = blockIdx.x, ct = blockIdx.y, bb = blockIdx.z;
    const int tid = threadIdx.x;
    const float* xp = x + ((size_t)(b0 + bb) * 256 + ct * 64) * 4096 + nt * 64;
    {
        int cr = tid >> 2, q = tid & 3;
#pragma unroll
        for (int j = 0; j < 4; j++) {
            float4 v = *(const float4*)&xp[(size_t)cr * 4096 + q * 16 + j * 4];
            ushort4 o;
            o.x = f2bf(v.x); o.y = f2bf(v.y); o.z = f2bf(v.z); o.w = f2bf(v.w);
            *(ushort4*)&t[cr][q * 16 + j * 4] = o;
        }
    }
    __syncthreads();
    {
        int nr = tid >> 2, co = (tid & 3) * 16;
        u16* op = xbt + ((size_t)bb * 4096 + nt * 64 + nr) * 256 + ct * 64 + co;
        us8 o0, o1;
#pragma unroll
        for (int j = 0; j < 8; j++) { o0[j] = t[co + j][nr]; o1[j] = t[co + 8 + j][nr]; }
        *(us8*)op = o0;
        *(us8*)(op + 8) = o1;
    }
}

// ---------------- K2: qkv GEMM (768x256 @ 256xN) ----------------
__global__ __launch_bounds__(256) void k_qkv_mm(const u16* __restrict__ xbt,
                                                const u16* __restrict__ wqb,
                                                u16* __restrict__ qkvb) {
    const int bid = blockIdx.x;
    const int mt = bid % 6, nt = bid / 6;
    const int m0 = mt * 128;
    const int cg = nt * 128;
    const int bb = cg >> 12, p0 = cg & 4095;
    const int tid = threadIdx.x, lane = tid & 63, w = tid >> 6;
    const int wm = w >> 1, wn = w & 1;
    const u16* aptr = xbt + ((size_t)bb * 4096 + p0 + wn * 64 + (lane & 15)) * 256 + (lane >> 4) * 8;
    const u16* bptr = wqb + (size_t)(m0 + wm * 64 + (lane & 15)) * 256 + (lane >> 4) * 8;

    f32x4 acc[4][4] = {};
#pragma unroll
    for (int ks = 0; ks < 8; ks++) {
        short8v af[4], bf[4];
#pragma unroll
        for (int i = 0; i < 4; i++) {
            af[i] = *(const short8v*)(aptr + (size_t)i * 16 * 256 + ks * 32);
            bf[i] = *(const short8v*)(bptr + (size_t)i * 16 * 256 + ks * 32);
        }
#pragma unroll
        for (int nf = 0; nf < 4; nf++)
#pragma unroll
            for (int mf = 0; mf < 4; mf++)
                acc[nf][mf] = __builtin_amdgcn_mfma_f32_16x16x32_bf16(af[nf], bf[mf], acc[nf][mf], 0, 0, 0);
    }
    const int mbase = m0 + wm * 64 + (lane & 15);
    const int nbase = p0 + wn * 64 + (lane >> 4) * 4;
#pragma unroll
    for (int nf = 0; nf < 4; nf++)
#pragma unroll
        for (int mf = 0; mf < 4; mf++) {
            int c = mbase + mf * 16;
            int nn = nbase + nf * 16;
            ushort4 o;
            o.x = f2bf(acc[nf][mf][0]);
            o.y = f2bf(acc[nf][mf][1]);
            o.z = f2bf(acc[nf][mf][2]);
            o.w = f2bf(acc[nf][mf][3]);
            *(ushort4*)(qkvb + ((size_t)bb * 768 + c) * 4096 + nn) = o;
        }
}

// ---------------- K3: fused depthwise 5x5 + grouped pointwise ----------------
__global__ __launch_bounds__(256) void k_dwpw(const u16* __restrict__ qkvb,
                                              const float* __restrict__ wdw,
                                              const float* __restrict__ wpw,
                                              u16* __restrict__ aggb) {
    __shared__ float dwt[16 * 4 * 68];
    const int tid = threadIdx.x;
    const int yt = blockIdx.x, g = blockIdx.y, bb = blockIdx.z;

    {
        const int cl = tid >> 4, xq = tid & 15;
        const int c = g * 16 + cl;
        const u16* in = qkvb + ((size_t)bb * 768 + c) * 4096;
        float w[5][5];
#pragma unroll
        for (int dy = 0; dy < 5; dy++)
#pragma unroll
            for (int dx = 0; dx < 5; dx++) w[dy][dx] = wdw[c * 25 + dy * 5 + dx];
        const int x0 = xq * 4;
#pragma unroll
        for (int ry = 0; ry < 4; ry++) {
            int y = yt * 4 + ry;
            float o0 = 0.f, o1 = 0.f, o2 = 0.f, o3 = 0.f;
#pragma unroll
            for (int dy = 0; dy < 5; dy++) {
                int yy = y + dy - 2;
                if (yy < 0 || yy > 63) continue;
                const u16* row = in + yy * 64;
                float4 v0 = (x0 >= 4) ? ld4bf(row + x0 - 4) : make_float4(0, 0, 0, 0);
                float4 v1 = ld4bf(row + x0);
                float4 v2 = (x0 + 4 < 64) ? ld4bf(row + x0 + 4) : make_float4(0, 0, 0, 0);
                float win[8] = {v0.z, v0.w, v1.x, v1.y, v1.z, v1.w, v2.x, v2.y};
#pragma unroll
                for (int dx = 0; dx < 5; dx++) {
                    float wv = w[dy][dx];
                    o0 += win[0 + dx] * wv;
                    o1 += win[1 + dx] * wv;
                    o2 += win[2 + dx] * wv;
                    o3 += win[3 + dx] * wv;
                }
            }
            float4 ov = make_float4(o0, o1, o2, o3);
            *(float4*)&dwt[(cl * 4 + ry) * 68 + x0] = ov;
        }
    }
    __syncthreads();

    {
        const int op = tid >> 5, xo = tid & 31;
        float wv[2][16];
#pragma unroll
        for (int oo = 0; oo < 2; oo++)
#pragma unroll
            for (int ic = 0; ic < 16; ic++)
                wv[oo][ic] = wpw[(size_t)(g * 16 + op * 2 + oo) * 16 + ic];
        float acc[2][4][2];
#pragma unroll
        for (int oo = 0; oo < 2; oo++)
#pragma unroll
            for (int j = 0; j < 4; j++) { acc[oo][j][0] = 0.f; acc[oo][j][1] = 0.f; }
#pragma unroll
        for (int ic = 0; ic < 16; ic++) {
#pragma unroll
            for (int j = 0; j < 4; j++) {
                float2 f = *(const float2*)&dwt[(ic * 4 + j) * 68 + xo * 2];
#pragma unroll
                for (int oo = 0; oo < 2; oo++) {
                    acc[oo][j][0] += wv[oo][ic] * f.x;
                    acc[oo][j][1] += wv[oo][ic] * f.y;
                }
            }
        }
#pragma unroll
        for (int oo = 0; oo < 2; oo++) {
            u16* outp = aggb + ((size_t)bb * 768 + g * 16 + op * 2 + oo) * 4096 + yt * 256;
#pragma unroll
            for (int j = 0; j < 4; j++) {
                ushort2 o;
                o.x = f2bf(acc[oo][j][0]);
                o.y = f2bf(acc[oo][j][1]);
                *(ushort2*)&outp[j * 64 + xo * 2] = o;
            }
        }
    }
}

// ---------------- K4: linear attention, writes att_t[n][512] ----------------
__global__ __launch_bounds__(256) void k_attn(const u16* __restrict__ qkvb,
                                              const u16* __restrict__ aggb,
                                              u16* __restrict__ attt) {
    const int h = blockIdx.x, bb = blockIdx.y;
    const int tid = threadIdx.x;
    const u16* src = (h < 16) ? qkvb + ((size_t)bb * 768 + h * 48) * 4096
                              : aggb + ((size_t)bb * 768 + (h - 16) * 48) * 4096;
    __shared__ float part[16 * 16 * 17];
    __shared__ float vks[17][17];

    // pass 1: vk[d][e] = sum_n vpad[d][n] * relu(k[e][n])
    {
        const int e = tid & 15, jg = tid >> 4;
        const u16* kr = src + (size_t)(16 + e) * 4096 + jg * 256;
        const u16* vr = src + (size_t)32 * 4096 + jg * 256;
        float a[17];
#pragma unroll
        for (int d = 0; d < 17; d++) a[d] = 0.f;
        for (int i = 0; i < 64; i++) {
            float4 kv = ld4bf(kr + i * 4);
            kv.x = fmaxf(kv.x, 0.f);
            kv.y = fmaxf(kv.y, 0.f);
            kv.z = fmaxf(kv.z, 0.f);
            kv.w = fmaxf(kv.w, 0.f);
#pragma unroll
            for (int d = 0; d < 16; d++) {
                float4 vv = ld4bf(vr + (size_t)d * 4096 + i * 4);
                a[d] += vv.x * kv.x + vv.y * kv.y + vv.z * kv.z + vv.w * kv.w;
            }
            a[16] += kv.x + kv.y + kv.z + kv.w;
        }
#pragma unroll
        for (int d = 0; d < 17; d++) part[(jg * 16 + e) * 17 + d] = a[d];
    }
    __syncthreads();
    for (int idx = tid; idx < 272; idx += 256) {
        int e = idx & 15, d = idx >> 4;
        float s = 0.f;
#pragma unroll
        for (int jg = 0; jg < 16; jg++) s += part[(jg * 16 + e) * 17 + d];
        vks[d][e] = s;
    }
    __syncthreads();

    // pass 2: out[d][n] = (vk[d]*relu(q[:,n])) / denom -> att_t[n][h*16+d]
    {
        for (int i = 0; i < 4; i++) {
            int n = tid * 4 + i * 1024;
            float4 q4[16];
#pragma unroll
            for (int e = 0; e < 16; e++) {
                float4 q = ld4bf(src + (size_t)e * 4096 + n);
                q.x = fmaxf(q.x, 0.f);
                q.y = fmaxf(q.y, 0.f);
                q.z = fmaxf(q.z, 0.f);
                q.w = fmaxf(q.w, 0.f);
                q4[e] = q;
            }
            float dx = 0.f, dy = 0.f, dz = 0.f, dw = 0.f;
#pragma unroll
            for (int e = 0; e < 16; e++) {
                float w = vks[16][e];
                dx += w * q4[e].x;
                dy += w * q4[e].y;
                dz += w * q4[e].z;
                dw += w * q4[e].w;
            }
            float rx = 1.f / fmaxf(dx, 1e-15f);
            float ry = 1.f / fmaxf(dy, 1e-15f);
            float rz = 1.f / fmaxf(dz, 1e-15f);
            float rw = 1.f / fmaxf(dw, 1e-15f);
            us8 ov[4][2];
#pragma unroll
            for (int d = 0; d < 16; d++) {
                float ox = 0.f, oy = 0.f, oz = 0.f, ow = 0.f;
#pragma unroll
                for (int e = 0; e < 16; e++) {
                    float w = vks[d][e];
                    ox += w * q4[e].x;
                    oy += w * q4[e].y;
                    oz += w * q4[e].z;
                    ow += w * q4[e].w;
                }
                ov[0][d >> 3][d & 7] = f2bf(ox * rx);
                ov[1][d >> 3][d & 7] = f2bf(oy * ry);
                ov[2][d >> 3][d & 7] = f2bf(oz * rz);
                ov[3][d >> 3][d & 7] = f2bf(ow * rw);
            }
#pragma unroll
            for (int r = 0; r < 4; r++) {
                u16* op = attt + ((size_t)bb * 4096 + n + r) * 512 + h * 16;
                *(us8*)op = ov[r][0];
                *(us8*)(op + 8) = ov[r][1];
            }
        }
    }
}

// ---------------- K5: proj GEMM (256x512 @ 512xN) + BN ----------------
__global__ __launch_bounds__(256) void k_proj_mm(const u16* __restrict__ attt,
                                                 const u16* __restrict__ wpb,
                                                 const float* __restrict__ gamma,
                                                 const float* __restrict__ beta,
                                                 const float* __restrict__ mean,
                                                 const float* __restrict__ var,
                                                 float* __restrict__ out, int b0) {
    const int bid = blockIdx.x;
    const int mt = bid & 1, nt = bid >> 1;
    const int m0 = mt * 128;
    const int cg = nt * 128;
    const int bb = cg >> 12, p0 = cg & 4095;
    const int tid = threadIdx.x, lane = tid & 63, w = tid >> 6;
    const int wm = w >> 1, wn = w & 1;
    const u16* aptr = attt + ((size_t)bb * 4096 + p0 + wn * 64 + (lane & 15)) * 512 + (lane >> 4) * 8;
    const u16* bptr = wpb + (size_t)(m0 + wm * 64 + (lane & 15)) * 512 + (lane >> 4) * 8;

    f32x4 acc[4][4] = {};
#pragma unroll
    for (int ks = 0; ks < 16; ks++) {
        short8v af[4], bf[4];
#pragma unroll
        for (int i = 0; i < 4; i++) {
            af[i] = *(const short8v*)(aptr + (size_t)i * 16 * 512 + ks * 32);
            bf[i] = *(const short8v*)(bptr + (size_t)i * 16 * 512 + ks * 32);
        }
#pragma unroll
        for (int nf = 0; nf < 4; nf++)
#pragma unroll
            for (int mf = 0; mf < 4; mf++)
                acc[nf][mf] = __builtin_amdgcn_mfma_f32_16x16x32_bf16(af[nf], bf[mf], acc[nf][mf], 0, 0, 0);
    }
    const int mbase = m0 + wm * 64 + (lane & 15);
    const int nbase = p0 + wn * 64 + (lane >> 4) * 4;
    float ivv[4], bsv[4];
#pragma unroll
    for (int mf = 0; mf < 4; mf++) {
        int m = mbase + mf * 16;
        float iv = gamma[m] / sqrtf(var[m] + 1e-5f);
        ivv[mf] = iv;
        bsv[mf] = beta[m] - mean[m] * iv;
    }
#pragma unroll
    for (int nf = 0; nf < 4; nf++)
#pragma unroll
        for (int mf = 0; mf < 4; mf++) {
            float4 v;
            v.x = acc[nf][mf][0] * ivv[mf] + bsv[mf];
            v.y = acc[nf][mf][1] * ivv[mf] + bsv[mf];
            v.z = acc[nf][mf][2] * ivv[mf] + bsv[mf];
            v.w = acc[nf][mf][3] * ivv[mf] + bsv[mf];
            *(float4*)(out + ((size_t)(b0 + bb) * 256 + mbase + mf * 16) * 4096 + nbase + nf * 16) = v;
        }
}

extern "C" void kernel_launch(void* const* d_in, const int* in_sizes, int n_in,
                              void* d_out, int out_size, void* d_ws, size_t ws_size,
                              hipStream_t stream) {
    const float* x = (const float*)d_in[0];
    const float* wq = (const float*)d_in[1];
    const float* wdw = (const float*)d_in[2];
    const float* wpw = (const float*)d_in[3];
    const float* wp = (const float*)d_in[4];
    const float* gamma = (const float*)d_in[5];
    const float* beta = (const float*)d_in[6];
    const float* mean = (const float*)d_in[7];
    const float* var = (const float*)d_in[8];
    float* out = (float*)d_out;

    u16* ws = (u16*)d_ws;
    u16* xbt = ws;                                      // NBC*4096*256
    u16* qkvb = xbt + (size_t)NBC * 4096 * 256;         // NBC*768*4096
    u16* aggb = qkvb + (size_t)NBC * 768 * 4096;        // NBC*768*4096
    u16* attt = aggb + (size_t)NBC * 768 * 4096;        // NBC*4096*512
    u16* wqb = attt + (size_t)NBC * 4096 * 512;         // 768*256
    u16* wpb = wqb + 768 * 256;                         // 256*512

    k_cvt_w<<<768, 256, 0, stream>>>(wq, wp, wqb, wpb);
    for (int chunk = 0; chunk < 2; ++chunk) {
        int b0 = chunk * NBC;
        k_tr_x<<<dim3(64, 4, NBC), 256, 0, stream>>>(x, xbt, b0);
        k_qkv_mm<<<1536, 256, 0, stream>>>(xbt, wqb, qkvb);
        k_dwpw<<<dim3(16, 48, NBC), 256, 0, stream>>>(qkvb, wdw, wpw, aggb);
        k_attn<<<dim3(32, NBC), 256, 0, stream>>>(qkvb, aggb, attt);
        k_proj_mm<<<512, 256, 0, stream>>>(attt, wpb, gamma, beta, mean, var, out, b0);
    }
}

// Round 3
// 575.692 us; speedup vs baseline: 2.2315x; 1.1893x over previous
//
#include <hip/hip_runtime.h>
#include <math.h>

// LiteMLA bf16/MFMA pipeline. 2 chunks x 8 batches.
// K0 k_cvt_w : wq, wp fp32 -> bf16 (once)
// K1 k_tr_x  : x[c][n] fp32 -> xb_t[n][c] bf16
// K2 k_qkv_mm: qkv GEMM via mfma_f32_16x16x32_bf16, no-LDS direct frag loads
// K3 k_dwpw  : fused depthwise 5x5 + grouped pointwise, bf16 io, fp32 math
// K4 k_vk   : partial vk[17][16] per (h,bb,ns) -> ws fp32   (2048 blocks)
// K5 k_att2 : reduce partials + pass2, writes att_t[n][512] (2048 blocks)
// K6 k_proj_mm: proj GEMM + BN affine, fp32 out

#define NBC 8

typedef unsigned short u16;
typedef __attribute__((ext_vector_type(8))) short short8v;
typedef __attribute__((ext_vector_type(8))) unsigned short us8;
typedef __attribute__((ext_vector_type(4))) float f32x4;

__device__ __forceinline__ u16 f2bf(float f) {
    union { float f; unsigned u; } v; v.f = f;
    unsigned r = v.u + 0x7fffu + ((v.u >> 16) & 1u);
    return (u16)(r >> 16);
}
__device__ __forceinline__ float bf2f(u16 u) {
    union { unsigned u; float f; } v; v.u = ((unsigned)u) << 16;
    return v.f;
}
__device__ __forceinline__ float4 ld4bf(const u16* p) {
    ushort4 u = *(const ushort4*)p;
    return make_float4(bf2f(u.x), bf2f(u.y), bf2f(u.z), bf2f(u.w));
}

// ---------------- K0: weight conversion ----------------
__global__ __launch_bounds__(256) void k_cvt_w(const float* __restrict__ wq,
                                               const float* __restrict__ wp,
                                               u16* __restrict__ wqb, u16* __restrict__ wpb) {
    int i = blockIdx.x * 256 + threadIdx.x;
    if (i < 768 * 256) wqb[i] = f2bf(wq[i]);
    if (i < 256 * 512) wpb[i] = f2bf(wp[i]);
}

// ---------------- K1: transpose x -> xb_t bf16 ----------------
__global__ __launch_bounds__(256) void k_tr_x(const float* __restrict__ x,
                                              u16* __restrict__ xbt, int b0) {
    __shared__ u16 t[64][72];
    const int nt = blockIdx.x, ct = blockIdx.y, bb = blockIdx.z;
    const int tid = threadIdx.x;
    const float* xp = x + ((size_t)(b0 + bb) * 256 + ct * 64) * 4096 + nt * 64;
    {
        int cr = tid >> 2, q = tid & 3;
#pragma unroll
        for (int j = 0; j < 4; j++) {
            float4 v = *(const float4*)&xp[(size_t)cr * 4096 + q * 16 + j * 4];
            ushort4 o;
            o.x = f2bf(v.x); o.y = f2bf(v.y); o.z = f2bf(v.z); o.w = f2bf(v.w);
            *(ushort4*)&t[cr][q * 16 + j * 4] = o;
        }
    }
    __syncthreads();
    {
        int nr = tid >> 2, co = (tid & 3) * 16;
        u16* op = xbt + ((size_t)bb * 4096 + nt * 64 + nr) * 256 + ct * 64 + co;
        us8 o0, o1;
#pragma unroll
        for (int j = 0; j < 8; j++) { o0[j] = t[co + j][nr]; o1[j] = t[co + 8 + j][nr]; }
        *(us8*)op = o0;
        *(us8*)(op + 8) = o1;
    }
}

// ---------------- K2: qkv GEMM (768x256 @ 256xN) ----------------
__global__ __launch_bounds__(256) void k_qkv_mm(const u16* __restrict__ xbt,
                                                const u16* __restrict__ wqb,
                                                u16* __restrict__ qkvb) {
    const int bid = blockIdx.x;
    const int mt = bid % 6, nt = bid / 6;
    const int m0 = mt * 128;
    const int cg = nt * 128;
    const int bb = cg >> 12, p0 = cg & 4095;
    const int tid = threadIdx.x, lane = tid & 63, w = tid >> 6;
    const int wm = w >> 1, wn = w & 1;
    const u16* aptr = xbt + ((size_t)bb * 4096 + p0 + wn * 64 + (lane & 15)) * 256 + (lane >> 4) * 8;
    const u16* bptr = wqb + (size_t)(m0 + wm * 64 + (lane & 15)) * 256 + (lane >> 4) * 8;

    f32x4 acc[4][4] = {};
#pragma unroll
    for (int ks = 0; ks < 8; ks++) {
        short8v af[4], bf[4];
#pragma unroll
        for (int i = 0; i < 4; i++) {
            af[i] = *(const short8v*)(aptr + (size_t)i * 16 * 256 + ks * 32);
            bf[i] = *(const short8v*)(bptr + (size_t)i * 16 * 256 + ks * 32);
        }
#pragma unroll
        for (int nf = 0; nf < 4; nf++)
#pragma unroll
            for (int mf = 0; mf < 4; mf++)
                acc[nf][mf] = __builtin_amdgcn_mfma_f32_16x16x32_bf16(af[nf], bf[mf], acc[nf][mf], 0, 0, 0);
    }
    const int mbase = m0 + wm * 64 + (lane & 15);
    const int nbase = p0 + wn * 64 + (lane >> 4) * 4;
#pragma unroll
    for (int nf = 0; nf < 4; nf++)
#pragma unroll
        for (int mf = 0; mf < 4; mf++) {
            int c = mbase + mf * 16;
            int nn = nbase + nf * 16;
            ushort4 o;
            o.x = f2bf(acc[nf][mf][0]);
            o.y = f2bf(acc[nf][mf][1]);
            o.z = f2bf(acc[nf][mf][2]);
            o.w = f2bf(acc[nf][mf][3]);
            *(ushort4*)(qkvb + ((size_t)bb * 768 + c) * 4096 + nn) = o;
        }
}

// ---------------- K3: fused depthwise 5x5 + grouped pointwise ----------------
__global__ __launch_bounds__(256) void k_dwpw(const u16* __restrict__ qkvb,
                                              const float* __restrict__ wdw,
                                              const float* __restrict__ wpw,
                                              u16* __restrict__ aggb) {
    __shared__ float dwt[16 * 4 * 68];
    const int tid = threadIdx.x;
    const int yt = blockIdx.x, g = blockIdx.y, bb = blockIdx.z;

    {
        const int cl = tid >> 4, xq = tid & 15;
        const int c = g * 16 + cl;
        const u16* in = qkvb + ((size_t)bb * 768 + c) * 4096;
        float w[5][5];
#pragma unroll
        for (int dy = 0; dy < 5; dy++)
#pragma unroll
            for (int dx = 0; dx < 5; dx++) w[dy][dx] = wdw[c * 25 + dy * 5 + dx];
        const int x0 = xq * 4;
#pragma unroll
        for (int ry = 0; ry < 4; ry++) {
            int y = yt * 4 + ry;
            float o0 = 0.f, o1 = 0.f, o2 = 0.f, o3 = 0.f;
#pragma unroll
            for (int dy = 0; dy < 5; dy++) {
                int yy = y + dy - 2;
                if (yy < 0 || yy > 63) continue;
                const u16* row = in + yy * 64;
                float4 v0 = (x0 >= 4) ? ld4bf(row + x0 - 4) : make_float4(0, 0, 0, 0);
                float4 v1 = ld4bf(row + x0);
                float4 v2 = (x0 + 4 < 64) ? ld4bf(row + x0 + 4) : make_float4(0, 0, 0, 0);
                float win[8] = {v0.z, v0.w, v1.x, v1.y, v1.z, v1.w, v2.x, v2.y};
#pragma unroll
                for (int dx = 0; dx < 5; dx++) {
                    float wv = w[dy][dx];
                    o0 += win[0 + dx] * wv;
                    o1 += win[1 + dx] * wv;
                    o2 += win[2 + dx] * wv;
                    o3 += win[3 + dx] * wv;
                }
            }
            float4 ov = make_float4(o0, o1, o2, o3);
            *(float4*)&dwt[(cl * 4 + ry) * 68 + x0] = ov;
        }
    }
    __syncthreads();

    {
        const int op = tid >> 5, xo = tid & 31;
        float wv[2][16];
#pragma unroll
        for (int oo = 0; oo < 2; oo++)
#pragma unroll
            for (int ic = 0; ic < 16; ic++)
                wv[oo][ic] = wpw[(size_t)(g * 16 + op * 2 + oo) * 16 + ic];
        float acc[2][4][2];
#pragma unroll
        for (int oo = 0; oo < 2; oo++)
#pragma unroll
            for (int j = 0; j < 4; j++) { acc[oo][j][0] = 0.f; acc[oo][j][1] = 0.f; }
#pragma unroll
        for (int ic = 0; ic < 16; ic++) {
#pragma unroll
            for (int j = 0; j < 4; j++) {
                float2 f = *(const float2*)&dwt[(ic * 4 + j) * 68 + xo * 2];
#pragma unroll
                for (int oo = 0; oo < 2; oo++) {
                    acc[oo][j][0] += wv[oo][ic] * f.x;
                    acc[oo][j][1] += wv[oo][ic] * f.y;
                }
            }
        }
#pragma unroll
        for (int oo = 0; oo < 2; oo++) {
            u16* outp = aggb + ((size_t)bb * 768 + g * 16 + op * 2 + oo) * 4096 + yt * 256;
#pragma unroll
            for (int j = 0; j < 4; j++) {
                ushort2 o;
                o.x = f2bf(acc[oo][j][0]);
                o.y = f2bf(acc[oo][j][1]);
                *(ushort2*)&outp[j * 64 + xo * 2] = o;
            }
        }
    }
}

// ---------------- K4: partial vk[17][16] per (h,bb,ns) ----------------
__global__ __launch_bounds__(256) void k_vk(const u16* __restrict__ qkvb,
                                            const u16* __restrict__ aggb,
                                            float* __restrict__ gpart) {
    // grid (32 h, NBC bb, 8 ns); block covers 512 cols
    const int h = blockIdx.x, bb = blockIdx.y, ns = blockIdx.z;
    const int tid = threadIdx.x;
    const u16* src = (h < 16) ? qkvb + ((size_t)bb * 768 + h * 48) * 4096
                              : aggb + ((size_t)bb * 768 + (h - 16) * 48) * 4096;
    __shared__ float part[16 * 16 * 17];
    const int e = tid & 15, jg = tid >> 4;
    const int c0 = ns * 512 + jg * 32;
    const u16* kr = src + (size_t)(16 + e) * 4096 + c0;
    const u16* vr = src + (size_t)32 * 4096 + c0;
    float a[17];
#pragma unroll
    for (int d = 0; d < 17; d++) a[d] = 0.f;
#pragma unroll
    for (int i = 0; i < 8; i++) {
        float4 kv = ld4bf(kr + i * 4);
        kv.x = fmaxf(kv.x, 0.f);
        kv.y = fmaxf(kv.y, 0.f);
        kv.z = fmaxf(kv.z, 0.f);
        kv.w = fmaxf(kv.w, 0.f);
#pragma unroll
        for (int d = 0; d < 16; d++) {
            float4 vv = ld4bf(vr + (size_t)d * 4096 + i * 4);
            a[d] += vv.x * kv.x + vv.y * kv.y + vv.z * kv.z + vv.w * kv.w;
        }
        a[16] += kv.x + kv.y + kv.z + kv.w;
    }
#pragma unroll
    for (int d = 0; d < 17; d++) part[(jg * 16 + e) * 17 + d] = a[d];
    __syncthreads();
    for (int idx = tid; idx < 272; idx += 256) {
        int e2 = idx & 15, d2 = idx >> 4;
        float s = 0.f;
#pragma unroll
        for (int j = 0; j < 16; j++) s += part[(j * 16 + e2) * 17 + d2];
        gpart[(((size_t)h * NBC + bb) * 8 + ns) * 272 + idx] = s;
    }
}

// ---------------- K5: reduce partials + attention pass 2 ----------------
__global__ __launch_bounds__(256) void k_att2(const u16* __restrict__ qkvb,
                                              const u16* __restrict__ aggb,
                                              const float* __restrict__ gpart,
                                              u16* __restrict__ attt) {
    // grid (32 h, NBC bb, 8 ns); thread handles 2 cols
    const int h = blockIdx.x, bb = blockIdx.y, ns = blockIdx.z;
    const int tid = threadIdx.x;
    const u16* src = (h < 16) ? qkvb + ((size_t)bb * 768 + h * 48) * 4096
                              : aggb + ((size_t)bb * 768 + (h - 16) * 48) * 4096;
    __shared__ float vks[17][16];
    for (int idx = tid; idx < 272; idx += 256) {
        float s = 0.f;
#pragma unroll
        for (int k = 0; k < 8; k++)
            s += gpart[(((size_t)h * NBC + bb) * 8 + k) * 272 + idx];
        vks[idx >> 4][idx & 15] = s;
    }
    __syncthreads();

    const int n = ns * 512 + tid * 2;
    float2 q2[16];
#pragma unroll
    for (int e = 0; e < 16; e++) {
        ushort2 u = *(const ushort2*)(src + (size_t)e * 4096 + n);
        q2[e] = make_float2(fmaxf(bf2f(u.x), 0.f), fmaxf(bf2f(u.y), 0.f));
    }
    float dx = 0.f, dy = 0.f;
#pragma unroll
    for (int e = 0; e < 16; e++) {
        float w = vks[16][e];
        dx += w * q2[e].x;
        dy += w * q2[e].y;
    }
    float rx = 1.f / fmaxf(dx, 1e-15f);
    float ry = 1.f / fmaxf(dy, 1e-15f);
    us8 o0a, o0b, o1a, o1b;
#pragma unroll
    for (int d = 0; d < 16; d++) {
        float ox = 0.f, oy = 0.f;
#pragma unroll
        for (int e = 0; e < 16; e++) {
            float w = vks[d][e];
            ox += w * q2[e].x;
            oy += w * q2[e].y;
        }
        u16 bx = f2bf(ox * rx), by = f2bf(oy * ry);
        if (d < 8) { o0a[d] = bx; o1a[d] = by; }
        else       { o0b[d - 8] = bx; o1b[d - 8] = by; }
    }
    u16* op = attt + ((size_t)bb * 4096 + n) * 512 + h * 16;
    *(us8*)op = o0a;
    *(us8*)(op + 8) = o0b;
    *(us8*)(op + 512) = o1a;
    *(us8*)(op + 520) = o1b;
}

// ---------------- K6: proj GEMM (256x512 @ 512xN) + BN ----------------
__global__ __launch_bounds__(256) void k_proj_mm(const u16* __restrict__ attt,
                                                 const u16* __restrict__ wpb,
                                                 const float* __restrict__ gamma,
                                                 const float* __restrict__ beta,
                                                 const float* __restrict__ mean,
                                                 const float* __restrict__ var,
                                                 float* __restrict__ out, int b0) {
    const int bid = blockIdx.x;
    const int mt = bid & 1, nt = bid >> 1;
    const int m0 = mt * 128;
    const int cg = nt * 128;
    const int bb = cg >> 12, p0 = cg & 4095;
    const int tid = threadIdx.x, lane = tid & 63, w = tid >> 6;
    const int wm = w >> 1, wn = w & 1;
    const u16* aptr = attt + ((size_t)bb * 4096 + p0 + wn * 64 + (lane & 15)) * 512 + (lane >> 4) * 8;
    const u16* bptr = wpb + (size_t)(m0 + wm * 64 + (lane & 15)) * 512 + (lane >> 4) * 8;

    f32x4 acc[4][4] = {};
#pragma unroll
    for (int ks = 0; ks < 16; ks++) {
        short8v af[4], bf[4];
#pragma unroll
        for (int i = 0; i < 4; i++) {
            af[i] = *(const short8v*)(aptr + (size_t)i * 16 * 512 + ks * 32);
            bf[i] = *(const short8v*)(bptr + (size_t)i * 16 * 512 + ks * 32);
        }
#pragma unroll
        for (int nf = 0; nf < 4; nf++)
#pragma unroll
            for (int mf = 0; mf < 4; mf++)
                acc[nf][mf] = __builtin_amdgcn_mfma_f32_16x16x32_bf16(af[nf], bf[mf], acc[nf][mf], 0, 0, 0);
    }
    const int mbase = m0 + wm * 64 + (lane & 15);
    const int nbase = p0 + wn * 64 + (lane >> 4) * 4;
    float ivv[4], bsv[4];
#pragma unroll
    for (int mf = 0; mf < 4; mf++) {
        int m = mbase + mf * 16;
        float iv = gamma[m] / sqrtf(var[m] + 1e-5f);
        ivv[mf] = iv;
        bsv[mf] = beta[m] - mean[m] * iv;
    }
#pragma unroll
    for (int nf = 0; nf < 4; nf++)
#pragma unroll
        for (int mf = 0; mf < 4; mf++) {
            float4 v;
            v.x = acc[nf][mf][0] * ivv[mf] + bsv[mf];
            v.y = acc[nf][mf][1] * ivv[mf] + bsv[mf];
            v.z = acc[nf][mf][2] * ivv[mf] + bsv[mf];
            v.w = acc[nf][mf][3] * ivv[mf] + bsv[mf];
            *(float4*)(out + ((size_t)(b0 + bb) * 256 + mbase + mf * 16) * 4096 + nbase + nf * 16) = v;
        }
}

extern "C" void kernel_launch(void* const* d_in, const int* in_sizes, int n_in,
                              void* d_out, int out_size, void* d_ws, size_t ws_size,
                              hipStream_t stream) {
    const float* x = (const float*)d_in[0];
    const float* wq = (const float*)d_in[1];
    const float* wdw = (const float*)d_in[2];
    const float* wpw = (const float*)d_in[3];
    const float* wp = (const float*)d_in[4];
    const float* gamma = (const float*)d_in[5];
    const float* beta = (const float*)d_in[6];
    const float* mean = (const float*)d_in[7];
    const float* var = (const float*)d_in[8];
    float* out = (float*)d_out;

    u16* ws = (u16*)d_ws;
    u16* xbt = ws;                                      // NBC*4096*256
    u16* qkvb = xbt + (size_t)NBC * 4096 * 256;         // NBC*768*4096
    u16* aggb = qkvb + (size_t)NBC * 768 * 4096;        // NBC*768*4096
    u16* attt = aggb + (size_t)NBC * 768 * 4096;        // NBC*4096*512
    u16* wqb = attt + (size_t)NBC * 4096 * 512;         // 768*256
    u16* wpb = wqb + 768 * 256;                         // 256*512
    float* gpart = (float*)(wpb + 256 * 512);           // 32*NBC*8*272 fp32

    k_cvt_w<<<768, 256, 0, stream>>>(wq, wp, wqb, wpb);
    for (int chunk = 0; chunk < 2; ++chunk) {
        int b0 = chunk * NBC;
        k_tr_x<<<dim3(64, 4, NBC), 256, 0, stream>>>(x, xbt, b0);
        k_qkv_mm<<<1536, 256, 0, stream>>>(xbt, wqb, qkvb);
        k_dwpw<<<dim3(16, 48, NBC), 256, 0, stream>>>(qkvb, wdw, wpw, aggb);
        k_vk<<<dim3(32, NBC, 8), 256, 0, stream>>>(qkvb, aggb, gpart);
        k_att2<<<dim3(32, NBC, 8), 256, 0, stream>>>(qkvb, aggb, gpart, attt);
        k_proj_mm<<<512, 256, 0, stream>>>(attt, wpb, gamma, beta, mean, var, out, b0);
    }
}

// Round 5
// 544.793 us; speedup vs baseline: 2.3581x; 1.0567x over previous
//
#include <hip/hip_runtime.h>
#include <math.h>

// LiteMLA bf16/MFMA pipeline. 2 chunks x 8 batches.
// K0 k_cvt_w : wq, wp fp32 -> bf16 (once)
// K1 k_tr_x  : x[c][n] fp32 -> xb_t[n][c] bf16
// K2 k_qkv_mm: qkv GEMM via mfma_f32_16x16x32_bf16, no-LDS direct frag loads
// K3 k_dwpw  : fused depthwise 5x5 + grouped pointwise, bf16 io, fp32 math
//              v2: dw input rows hoisted to registers (1 load pass), float4 pw
// K4 k_vk   : partial vk[17][16] per (h,bb,ns) -> ws fp32   (2048 blocks)
// K5 k_att2 : reduce partials + pass2, writes att_t[n][512] (2048 blocks)
// K6 k_proj_mm: proj GEMM + BN affine, fp32 out

#define NBC 8

typedef unsigned short u16;
typedef __attribute__((ext_vector_type(8))) short short8v;
typedef __attribute__((ext_vector_type(8))) unsigned short us8;
typedef __attribute__((ext_vector_type(4))) float f32x4;

__device__ __forceinline__ u16 f2bf(float f) {
    union { float f; unsigned u; } v; v.f = f;
    unsigned r = v.u + 0x7fffu + ((v.u >> 16) & 1u);
    return (u16)(r >> 16);
}
__device__ __forceinline__ float bf2f(u16 u) {
    union { unsigned u; float f; } v; v.u = ((unsigned)u) << 16;
    return v.f;
}
__device__ __forceinline__ float4 ld4bf(const u16* p) {
    ushort4 u = *(const ushort4*)p;
    return make_float4(bf2f(u.x), bf2f(u.y), bf2f(u.z), bf2f(u.w));
}

// ---------------- K0: weight conversion ----------------
__global__ __launch_bounds__(256) void k_cvt_w(const float* __restrict__ wq,
                                               const float* __restrict__ wp,
                                               u16* __restrict__ wqb, u16* __restrict__ wpb) {
    int i = blockIdx.x * 256 + threadIdx.x;
    if (i < 768 * 256) wqb[i] = f2bf(wq[i]);
    if (i < 256 * 512) wpb[i] = f2bf(wp[i]);
}

// ---------------- K1: transpose x -> xb_t bf16 ----------------
__global__ __launch_bounds__(256) void k_tr_x(const float* __restrict__ x,
                                              u16* __restrict__ xbt, int b0) {
    __shared__ u16 t[64][72];
    const int nt = blockIdx.x, ct = blockIdx.y, bb = blockIdx.z;
    const int tid = threadIdx.x;
    const float* xp = x + ((size_t)(b0 + bb) * 256 + ct * 64) * 4096 + nt * 64;
    {
        int cr = tid >> 2, q = tid & 3;
#pragma unroll
        for (int j = 0; j < 4; j++) {
            float4 v = *(const float4*)&xp[(size_t)cr * 4096 + q * 16 + j * 4];
            ushort4 o;
            o.x = f2bf(v.x); o.y = f2bf(v.y); o.z = f2bf(v.z); o.w = f2bf(v.w);
            *(ushort4*)&t[cr][q * 16 + j * 4] = o;
        }
    }
    __syncthreads();
    {
        int nr = tid >> 2, co = (tid & 3) * 16;
        u16* op = xbt + ((size_t)bb * 4096 + nt * 64 + nr) * 256 + ct * 64 + co;
        us8 o0, o1;
#pragma unroll
        for (int j = 0; j < 8; j++) { o0[j] = t[co + j][nr]; o1[j] = t[co + 8 + j][nr]; }
        *(us8*)op = o0;
        *(us8*)(op + 8) = o1;
    }
}

// ---------------- K2: qkv GEMM (768x256 @ 256xN) ----------------
__global__ __launch_bounds__(256) void k_qkv_mm(const u16* __restrict__ xbt,
                                                const u16* __restrict__ wqb,
                                                u16* __restrict__ qkvb) {
    const int bid = blockIdx.x;
    const int mt = bid % 6, nt = bid / 6;
    const int m0 = mt * 128;
    const int cg = nt * 128;
    const int bb = cg >> 12, p0 = cg & 4095;
    const int tid = threadIdx.x, lane = tid & 63, w = tid >> 6;
    const int wm = w >> 1, wn = w & 1;
    const u16* aptr = xbt + ((size_t)bb * 4096 + p0 + wn * 64 + (lane & 15)) * 256 + (lane >> 4) * 8;
    const u16* bptr = wqb + (size_t)(m0 + wm * 64 + (lane & 15)) * 256 + (lane >> 4) * 8;

    f32x4 acc[4][4] = {};
#pragma unroll
    for (int ks = 0; ks < 8; ks++) {
        short8v af[4], bf[4];
#pragma unroll
        for (int i = 0; i < 4; i++) {
            af[i] = *(const short8v*)(aptr + (size_t)i * 16 * 256 + ks * 32);
            bf[i] = *(const short8v*)(bptr + (size_t)i * 16 * 256 + ks * 32);
        }
#pragma unroll
        for (int nf = 0; nf < 4; nf++)
#pragma unroll
            for (int mf = 0; mf < 4; mf++)
                acc[nf][mf] = __builtin_amdgcn_mfma_f32_16x16x32_bf16(af[nf], bf[mf], acc[nf][mf], 0, 0, 0);
    }
    const int mbase = m0 + wm * 64 + (lane & 15);
    const int nbase = p0 + wn * 64 + (lane >> 4) * 4;
#pragma unroll
    for (int nf = 0; nf < 4; nf++)
#pragma unroll
        for (int mf = 0; mf < 4; mf++) {
            int c = mbase + mf * 16;
            int nn = nbase + nf * 16;
            ushort4 o;
            o.x = f2bf(acc[nf][mf][0]);
            o.y = f2bf(acc[nf][mf][1]);
            o.z = f2bf(acc[nf][mf][2]);
            o.w = f2bf(acc[nf][mf][3]);
            *(ushort4*)(qkvb + ((size_t)bb * 768 + c) * 4096 + nn) = o;
        }
}

// ---------------- K3: fused depthwise 5x5 + grouped pointwise (v2) ----------------
__global__ __launch_bounds__(256) void k_dwpw(const u16* __restrict__ qkvb,
                                              const float* __restrict__ wdw,
                                              const float* __restrict__ wpw,
                                              u16* __restrict__ aggb) {
    // grid: (yt 16, g 48, bb NBC); 4 output rows per block
    __shared__ float dwt[16 * 4 * 68];  // [ic][ry][x], row stride 68
    const int tid = threadIdx.x;
    const int yt = blockIdx.x, g = blockIdx.y, bb = blockIdx.z;
    const int cl = tid >> 4, xq = tid & 15;

    // ---- depthwise phase: register-resident 8x12px window, single load pass ----
    {
        const int c = g * 16 + cl;
        const u16* in = qkvb + ((size_t)bb * 768 + c) * 4096;
        float w[5][5];
#pragma unroll
        for (int dy = 0; dy < 5; dy++)
#pragma unroll
            for (int dx = 0; dx < 5; dx++) w[dy][dx] = wdw[c * 25 + dy * 5 + dx];
        const int x0 = xq * 4;

        float rows[8][8];  // [input row r = y-2 .. y+5][window px x0-2 .. x0+5]
#pragma unroll
        for (int r = 0; r < 8; r++) {
            int yy = yt * 4 + r - 2;
            if (yy < 0 || yy > 63) {
#pragma unroll
                for (int j = 0; j < 8; j++) rows[r][j] = 0.f;
            } else {
                const u16* rp = in + yy * 64;
                float4 v0 = (x0 >= 4) ? ld4bf(rp + x0 - 4) : make_float4(0, 0, 0, 0);
                float4 v1 = ld4bf(rp + x0);
                float4 v2 = (x0 + 4 < 64) ? ld4bf(rp + x0 + 4) : make_float4(0, 0, 0, 0);
                rows[r][0] = v0.z; rows[r][1] = v0.w;
                rows[r][2] = v1.x; rows[r][3] = v1.y;
                rows[r][4] = v1.z; rows[r][5] = v1.w;
                rows[r][6] = v2.x; rows[r][7] = v2.y;
            }
        }
#pragma unroll
        for (int ry = 0; ry < 4; ry++) {
            float o0 = 0.f, o1 = 0.f, o2 = 0.f, o3 = 0.f;
#pragma unroll
            for (int dy = 0; dy < 5; dy++) {
#pragma unroll
                for (int dx = 0; dx < 5; dx++) {
                    float wv = w[dy][dx];
                    o0 += rows[ry + dy][0 + dx] * wv;
                    o1 += rows[ry + dy][1 + dx] * wv;
                    o2 += rows[ry + dy][2 + dx] * wv;
                    o3 += rows[ry + dy][3 + dx] * wv;
                }
            }
            float4 ov = make_float4(o0, o1, o2, o3);
            *(float4*)&dwt[(cl * 4 + ry) * 68 + x0] = ov;
        }
    }
    __syncthreads();

    // ---- grouped pointwise phase: thread = (oc, 4px), float4 LDS reads ----
    {
        const int oc = cl;  // 16 output channels
        float wv[16];
#pragma unroll
        for (int ic = 0; ic < 16; ic++)
            wv[ic] = wpw[(size_t)(g * 16 + oc) * 16 + ic];
        const int x0 = xq * 4;
        float acc[4][4];
#pragma unroll
        for (int j = 0; j < 4; j++)
#pragma unroll
            for (int p = 0; p < 4; p++) acc[j][p] = 0.f;
#pragma unroll
        for (int ic = 0; ic < 16; ic++) {
            float wvv = wv[ic];
#pragma unroll
            for (int j = 0; j < 4; j++) {
                float4 f = *(const float4*)&dwt[(ic * 4 + j) * 68 + x0];
                acc[j][0] += wvv * f.x;
                acc[j][1] += wvv * f.y;
                acc[j][2] += wvv * f.z;
                acc[j][3] += wvv * f.w;
            }
        }
        u16* outp = aggb + ((size_t)bb * 768 + g * 16 + oc) * 4096 + yt * 256;
#pragma unroll
        for (int j = 0; j < 4; j++) {
            ushort4 o;
            o.x = f2bf(acc[j][0]);
            o.y = f2bf(acc[j][1]);
            o.z = f2bf(acc[j][2]);
            o.w = f2bf(acc[j][3]);
            *(ushort4*)&outp[j * 64 + x0] = o;
        }
    }
}

// ---------------- K4: partial vk[17][16] per (h,bb,ns) ----------------
__global__ __launch_bounds__(256) void k_vk(const u16* __restrict__ qkvb,
                                            const u16* __restrict__ aggb,
                                            float* __restrict__ gpart) {
    // grid (32 h, NBC bb, 8 ns); block covers 512 cols
    const int h = blockIdx.x, bb = blockIdx.y, ns = blockIdx.z;
    const int tid = threadIdx.x;
    const u16* src = (h < 16) ? qkvb + ((size_t)bb * 768 + h * 48) * 4096
                              : aggb + ((size_t)bb * 768 + (h - 16) * 48) * 4096;
    __shared__ float part[16 * 16 * 17];
    const int e = tid & 15, jg = tid >> 4;
    const int c0 = ns * 512 + jg * 32;
    const u16* kr = src + (size_t)(16 + e) * 4096 + c0;
    const u16* vr = src + (size_t)32 * 4096 + c0;
    float a[17];
#pragma unroll
    for (int d = 0; d < 17; d++) a[d] = 0.f;
#pragma unroll
    for (int i = 0; i < 8; i++) {
        float4 kv = ld4bf(kr + i * 4);
        kv.x = fmaxf(kv.x, 0.f);
        kv.y = fmaxf(kv.y, 0.f);
        kv.z = fmaxf(kv.z, 0.f);
        kv.w = fmaxf(kv.w, 0.f);
#pragma unroll
        for (int d = 0; d < 16; d++) {
            float4 vv = ld4bf(vr + (size_t)d * 4096 + i * 4);
            a[d] += vv.x * kv.x + vv.y * kv.y + vv.z * kv.z + vv.w * kv.w;
        }
        a[16] += kv.x + kv.y + kv.z + kv.w;
    }
#pragma unroll
    for (int d = 0; d < 17; d++) part[(jg * 16 + e) * 17 + d] = a[d];
    __syncthreads();
    for (int idx = tid; idx < 272; idx += 256) {
        int e2 = idx & 15, d2 = idx >> 4;
        float s = 0.f;
#pragma unroll
        for (int j = 0; j < 16; j++) s += part[(j * 16 + e2) * 17 + d2];
        gpart[(((size_t)h * NBC + bb) * 8 + ns) * 272 + idx] = s;
    }
}

// ---------------- K5: reduce partials + attention pass 2 ----------------
__global__ __launch_bounds__(256) void k_att2(const u16* __restrict__ qkvb,
                                              const u16* __restrict__ aggb,
                                              const float* __restrict__ gpart,
                                              u16* __restrict__ attt) {
    // grid (32 h, NBC bb, 8 ns); thread handles 2 cols
    const int h = blockIdx.x, bb = blockIdx.y, ns = blockIdx.z;
    const int tid = threadIdx.x;
    const u16* src = (h < 16) ? qkvb + ((size_t)bb * 768 + h * 48) * 4096
                              : aggb + ((size_t)bb * 768 + (h - 16) * 48) * 4096;
    __shared__ float vks[17][16];
    for (int idx = tid; idx < 272; idx += 256) {
        float s = 0.f;
#pragma unroll
        for (int k = 0; k < 8; k++)
            s += gpart[(((size_t)h * NBC + bb) * 8 + k) * 272 + idx];
        vks[idx >> 4][idx & 15] = s;
    }
    __syncthreads();

    const int n = ns * 512 + tid * 2;
    float2 q2[16];
#pragma unroll
    for (int e = 0; e < 16; e++) {
        ushort2 u = *(const ushort2*)(src + (size_t)e * 4096 + n);
        q2[e] = make_float2(fmaxf(bf2f(u.x), 0.f), fmaxf(bf2f(u.y), 0.f));
    }
    float dx = 0.f, dy = 0.f;
#pragma unroll
    for (int e = 0; e < 16; e++) {
        float w = vks[16][e];
        dx += w * q2[e].x;
        dy += w * q2[e].y;
    }
    float rx = 1.f / fmaxf(dx, 1e-15f);
    float ry = 1.f / fmaxf(dy, 1e-15f);
    us8 o0a, o0b, o1a, o1b;
#pragma unroll
    for (int d = 0; d < 16; d++) {
        float ox = 0.f, oy = 0.f;
#pragma unroll
        for (int e = 0; e < 16; e++) {
            float w = vks[d][e];
            ox += w * q2[e].x;
            oy += w * q2[e].y;
        }
        u16 bx = f2bf(ox * rx), by = f2bf(oy * ry);
        if (d < 8) { o0a[d] = bx; o1a[d] = by; }
        else       { o0b[d - 8] = bx; o1b[d - 8] = by; }
    }
    u16* op = attt + ((size_t)bb * 4096 + n) * 512 + h * 16;
    *(us8*)op = o0a;
    *(us8*)(op + 8) = o0b;
    *(us8*)(op + 512) = o1a;
    *(us8*)(op + 520) = o1b;
}

// ---------------- K6: proj GEMM (256x512 @ 512xN) + BN ----------------
__global__ __launch_bounds__(256) void k_proj_mm(const u16* __restrict__ attt,
                                                 const u16* __restrict__ wpb,
                                                 const float* __restrict__ gamma,
                                                 const float* __restrict__ beta,
                                                 const float* __restrict__ mean,
                                                 const float* __restrict__ var,
                                                 float* __restrict__ out, int b0) {
    const int bid = blockIdx.x;
    const int mt = bid & 1, nt = bid >> 1;
    const int m0 = mt * 128;
    const int cg = nt * 128;
    const int bb = cg >> 12, p0 = cg & 4095;
    const int tid = threadIdx.x, lane = tid & 63, w = tid >> 6;
    const int wm = w >> 1, wn = w & 1;
    const u16* aptr = attt + ((size_t)bb * 4096 + p0 + wn * 64 + (lane & 15)) * 512 + (lane >> 4) * 8;
    const u16* bptr = wpb + (size_t)(m0 + wm * 64 + (lane & 15)) * 512 + (lane >> 4) * 8;

    f32x4 acc[4][4] = {};
#pragma unroll
    for (int ks = 0; ks < 16; ks++) {
        short8v af[4], bf[4];
#pragma unroll
        for (int i = 0; i < 4; i++) {
            af[i] = *(const short8v*)(aptr + (size_t)i * 16 * 512 + ks * 32);
            bf[i] = *(const short8v*)(bptr + (size_t)i * 16 * 512 + ks * 32);
        }
#pragma unroll
        for (int nf = 0; nf < 4; nf++)
#pragma unroll
            for (int mf = 0; mf < 4; mf++)
                acc[nf][mf] = __builtin_amdgcn_mfma_f32_16x16x32_bf16(af[nf], bf[mf], acc[nf][mf], 0, 0, 0);
    }
    const int mbase = m0 + wm * 64 + (lane & 15);
    const int nbase = p0 + wn * 64 + (lane >> 4) * 4;
    float ivv[4], bsv[4];
#pragma unroll
    for (int mf = 0; mf < 4; mf++) {
        int m = mbase + mf * 16;
        float iv = gamma[m] / sqrtf(var[m] + 1e-5f);
        ivv[mf] = iv;
        bsv[mf] = beta[m] - mean[m] * iv;
    }
#pragma unroll
    for (int nf = 0; nf < 4; nf++)
#pragma unroll
        for (int mf = 0; mf < 4; mf++) {
            float4 v;
            v.x = acc[nf][mf][0] * ivv[mf] + bsv[mf];
            v.y = acc[nf][mf][1] * ivv[mf] + bsv[mf];
            v.z = acc[nf][mf][2] * ivv[mf] + bsv[mf];
            v.w = acc[nf][mf][3] * ivv[mf] + bsv[mf];
            *(float4*)(out + ((size_t)(b0 + bb) * 256 + mbase + mf * 16) * 4096 + nbase + nf * 16) = v;
        }
}

extern "C" void kernel_launch(void* const* d_in, const int* in_sizes, int n_in,
                              void* d_out, int out_size, void* d_ws, size_t ws_size,
                              hipStream_t stream) {
    const float* x = (const float*)d_in[0];
    const float* wq = (const float*)d_in[1];
    const float* wdw = (const float*)d_in[2];
    const float* wpw = (const float*)d_in[3];
    const float* wp = (const float*)d_in[4];
    const float* gamma = (const float*)d_in[5];
    const float* beta = (const float*)d_in[6];
    const float* mean = (const float*)d_in[7];
    const float* var = (const float*)d_in[8];
    float* out = (float*)d_out;

    u16* ws = (u16*)d_ws;
    u16* xbt = ws;                                      // NBC*4096*256
    u16* qkvb = xbt + (size_t)NBC * 4096 * 256;         // NBC*768*4096
    u16* aggb = qkvb + (size_t)NBC * 768 * 4096;        // NBC*768*4096
    u16* attt = aggb + (size_t)NBC * 768 * 4096;        // NBC*4096*512
    u16* wqb = attt + (size_t)NBC * 4096 * 512;         // 768*256
    u16* wpb = wqb + 768 * 256;                         // 256*512
    float* gpart = (float*)(wpb + 256 * 512);           // 32*NBC*8*272 fp32

    k_cvt_w<<<768, 256, 0, stream>>>(wq, wp, wqb, wpb);
    for (int chunk = 0; chunk < 2; ++chunk) {
        int b0 = chunk * NBC;
        k_tr_x<<<dim3(64, 4, NBC), 256, 0, stream>>>(x, xbt, b0);
        k_qkv_mm<<<1536, 256, 0, stream>>>(xbt, wqb, qkvb);
        k_dwpw<<<dim3(16, 48, NBC), 256, 0, stream>>>(qkvb, wdw, wpw, aggb);
        k_vk<<<dim3(32, NBC, 8), 256, 0, stream>>>(qkvb, aggb, gpart);
        k_att2<<<dim3(32, NBC, 8), 256, 0, stream>>>(qkvb, aggb, gpart, attt);
        k_proj_mm<<<512, 256, 0, stream>>>(attt, wpb, gamma, beta, mean, var, out, b0);
    }
}